// Round 1
// baseline (233.890 us; speedup 1.0000x reference)
//
#include <hip/hip_runtime.h>
#include <math.h>

#define H_IMG 2160
#define W_IMG 3840
#define TW 32
#define TH 8
#define EW (TW + 2)   // 34
#define EH (TH + 2)   // 10
#define NBINS 2048

// Fused: render (normal-from-depth + SH shading, masked) -> q = render - rgb
// -> diff = q - avgpool3x3(q) -> masked sum of diff^2 and mask count.
__global__ __launch_bounds__(256) void shading_main(
    const float* __restrict__ depth,
    const float* __restrict__ rgb,
    const int*   __restrict__ mask,
    const float* __restrict__ lmat,   // [9][3]
    const float* __restrict__ K,      // [3][3]
    float* __restrict__ accum)        // [NBINS][2] partial {S, C}
{
    __shared__ float q[EH][EW][3];
    __shared__ float sS[4], sC[4];

    const int tx  = threadIdx.x;          // 0..31
    const int ty  = threadIdx.y;          // 0..7
    const int tid = ty * TW + tx;         // 0..255
    const int w0  = blockIdx.x * TW;
    const int h0  = blockIdx.y * TH;

    // General 3x3 inverse of K (adjugate / det) — uniform across threads,
    // lands in SGPRs; ~30 flops, negligible.
    const float m00 = K[0], m01 = K[1], m02 = K[2];
    const float m10 = K[3], m11 = K[4], m12 = K[5];
    const float m20 = K[6], m21 = K[7], m22 = K[8];
    const float det = m00*(m11*m22 - m12*m21)
                    - m01*(m10*m22 - m12*m20)
                    + m02*(m10*m21 - m11*m20);
    const float id  = 1.0f / det;
    const float i00 = (m11*m22 - m12*m21) * id;
    const float i01 = (m02*m21 - m01*m22) * id;
    const float i02 = (m01*m12 - m02*m11) * id;
    const float i10 = (m12*m20 - m10*m22) * id;
    const float i11 = (m00*m22 - m02*m20) * id;
    const float i12 = (m02*m10 - m00*m12) * id;
    const float i20 = (m10*m21 - m11*m20) * id;
    const float i21 = (m01*m20 - m00*m21) * id;
    const float i22 = (m00*m11 - m01*m10) * id;

    float L[27];
    #pragma unroll
    for (int i = 0; i < 27; ++i) L[i] = lmat[i];   // uniform -> scalar loads

    // ---- Phase 1: fill q over the extended tile (zero outside image) ----
    for (int idx = tid; idx < EH * EW; idx += TW * TH) {
        const int er = idx / EW;
        const int ec = idx - er * EW;
        const int gh = h0 - 1 + er;
        const int gw = w0 - 1 + ec;
        float q0 = 0.f, q1 = 0.f, q2 = 0.f;
        if (gh >= 0 && gh < H_IMG && gw >= 0 && gw < W_IMG) {
            const int pix = gh * W_IMG + gw;
            const float r0 = rgb[pix*3+0], r1 = rgb[pix*3+1], r2 = rgb[pix*3+2];
            const int   mv = mask[pix];

            // back-projected ray at (gh,gw); neighbors differ by one Kinv column
            const float fw = (float)gw, fh = (float)gh;
            const float dxr = i00*fw + i01*fh + i02;
            const float dyr = i10*fw + i11*fh + i12;
            const float dzr = i20*fw + i21*fh + i22;

            const float d0 = depth[pix];
            const float px = dxr*d0, py = dyr*d0, pz = dzr*d0;

            float plx = 0.f, ply = 0.f, plz = 0.f;     // right neighbor (zero-pad)
            if (gw + 1 < W_IMG) {
                const float dl = depth[pix + 1];
                plx = (dxr + i00) * dl;
                ply = (dyr + i10) * dl;
                plz = (dzr + i20) * dl;
            }
            float pux = 0.f, puy = 0.f, puz = 0.f;     // down neighbor (zero-pad)
            if (gh + 1 < H_IMG) {
                const float du = depth[pix + W_IMG];
                pux = (dxr + i01) * du;
                puy = (dyr + i11) * du;
                puz = (dzr + i21) * du;
            }

            const float ax = plx - px, ay = ply - py, az = plz - pz;
            const float bx = pux - px, by = puy - py, bz = puz - pz;
            float nx = ay*bz - az*by;
            float ny = az*bx - ax*bz;
            float nz = ax*by - ay*bx;
            const float nn  = nx*nx + ny*ny + nz*nz;
            const float inr = 1.0f / fmaxf(sqrtf(nn), 1e-12f);
            nx *= inr; ny *= inr; nz *= inr;

            const float h4 = nx*ny, h5 = ny*nz, h7 = nz*nx;
            const float h6 = -nx*nx - ny*ny + 2.0f*nz*nz;
            const float h8 =  nx*nx - ny*ny;

            float B0 = L[0] + ny*L[3] + nz*L[6] + nx*L[9]  + h4*L[12] + h5*L[15] + h6*L[18] + h7*L[21] + h8*L[24];
            float B1 = L[1] + ny*L[4] + nz*L[7] + nx*L[10] + h4*L[13] + h5*L[16] + h6*L[19] + h7*L[22] + h8*L[25];
            float B2 = L[2] + ny*L[5] + nz*L[8] + nx*L[11] + h4*L[14] + h5*L[17] + h6*L[20] + h7*L[23] + h8*L[26];
            if (mv <= 0) { B0 = 0.f; B1 = 0.f; B2 = 0.f; }   // render = where(mask, B, 0)

            q0 = B0 - r0; q1 = B1 - r1; q2 = B2 - r2;
        }
        q[er][ec][0] = q0;
        q[er][ec][1] = q1;
        q[er][ec][2] = q2;
    }
    __syncthreads();

    // ---- Phase 2: diff = q - sum3x3(q)/9 at the center pixel ----
    const int gh  = h0 + ty;
    const int gw  = w0 + tx;
    const int pix = gh * W_IMG + gw;   // grid divides exactly: 2160=8*270, 3840=32*120

    float s0 = 0.f, s1 = 0.f, s2 = 0.f;
    #pragma unroll
    for (int dy2 = 0; dy2 < 3; ++dy2) {
        #pragma unroll
        for (int dx2 = 0; dx2 < 3; ++dx2) {
            s0 += q[ty + dy2][tx + dx2][0];
            s1 += q[ty + dy2][tx + dx2][1];
            s2 += q[ty + dy2][tx + dx2][2];
        }
    }
    const float c0 = q[ty+1][tx+1][0] - s0 * (1.0f/9.0f);
    const float c1 = q[ty+1][tx+1][1] - s1 * (1.0f/9.0f);
    const float c2 = q[ty+1][tx+1][2] - s2 * (1.0f/9.0f);

    float S = 0.f, C = 0.f;
    if (mask[pix] > 0) {               // L1/L2 hit: fetched in phase 1
        S = c0*c0 + c1*c1 + c2*c2;
        C = 1.f;
    }

    // ---- Phase 3: block reduce (wave64 shuffle + LDS) -> binned atomic ----
    #pragma unroll
    for (int off = 32; off > 0; off >>= 1) {
        S += __shfl_down(S, off, 64);
        C += __shfl_down(C, off, 64);
    }
    const int wid = tid >> 6, lane = tid & 63;
    if (lane == 0) { sS[wid] = S; sC[wid] = C; }
    __syncthreads();
    if (tid == 0) {
        const float ts = sS[0] + sS[1] + sS[2] + sS[3];
        const float tc = sC[0] + sC[1] + sC[2] + sC[3];
        const int bin = (blockIdx.y * gridDim.x + blockIdx.x) & (NBINS - 1);
        atomicAdd(&accum[2*bin + 0], ts);
        atomicAdd(&accum[2*bin + 1], tc);
    }
}

__global__ __launch_bounds__(256) void finalize_kernel(
    const float* __restrict__ accum, float* __restrict__ out)
{
    const int tid = threadIdx.x;
    float s = 0.f, c = 0.f;
    for (int i = tid; i < NBINS; i += 256) {
        s += accum[2*i + 0];
        c += accum[2*i + 1];
    }
    #pragma unroll
    for (int off = 32; off > 0; off >>= 1) {
        s += __shfl_down(s, off, 64);
        c += __shfl_down(c, off, 64);
    }
    __shared__ float sS[4], sC[4];
    const int wid = tid >> 6, lane = tid & 63;
    if (lane == 0) { sS[wid] = s; sC[wid] = c; }
    __syncthreads();
    if (tid == 0) {
        const float ts = sS[0] + sS[1] + sS[2] + sS[3];
        const float tc = sC[0] + sC[1] + sC[2] + sC[3];
        out[0] = ts / (3.0f * tc);
    }
}

extern "C" void kernel_launch(void* const* d_in, const int* in_sizes, int n_in,
                              void* d_out, int out_size, void* d_ws, size_t ws_size,
                              hipStream_t stream) {
    const float* depth = (const float*)d_in[0];   // [2160][3840] f32
    const float* rgb   = (const float*)d_in[1];   // [2160][3840][3] f32
    const int*   mask  = (const int*)  d_in[2];   // [2160][3840] i32
    const float* lmat  = (const float*)d_in[3];   // [9][3] f32
    const float* K     = (const float*)d_in[4];   // [3][3] f32
    float* accum = (float*)d_ws;                  // NBINS*2 floats
    float* out   = (float*)d_out;                 // scalar loss

    hipMemsetAsync(accum, 0, NBINS * 2 * sizeof(float), stream);

    dim3 block(TW, TH);
    dim3 grid(W_IMG / TW, H_IMG / TH);            // 120 x 270 = 32400 blocks
    shading_main<<<grid, block, 0, stream>>>(depth, rgb, mask, lmat, K, accum);
    finalize_kernel<<<1, 256, 0, stream>>>(accum, out);
}

// Round 2
// 211.687 us; speedup vs baseline: 1.1049x; 1.1049x over previous
//
#include <hip/hip_runtime.h>
#include <math.h>

#define H_IMG 2160
#define W_IMG 3840
#define TW 64          // tile width  (centers)
#define TH 16          // tile height (centers)
#define EXT_ROWS 18    // rows h0-1 .. h0+16
#define EXT_COLS 72    // cols w0-4 .. w0+67 (4-aligned for float4 loads)
#define QPITCH 73      // LDS row pitch in float4 (pad +1: spreads rows by 4 banks)
#define NGROUPS 18     // 72 cols / 4
#define NUNITS (EXT_ROWS * NGROUPS)   // 324
#define NBINS 2048

// q = mask*B(normal(depth)) - rgb for one pixel; .w carries maskf.
__device__ __forceinline__ float4 shade_px(
    float rx, float ry, float rz,              // back-projected ray at this px
    float i00, float i10, float i20,           // Kinv col0 (x step)
    float i01, float i11, float i21,           // Kinv col1 (y step)
    float d0, float dR, float dD,              // depth: self, right, down (0 = zero-pad)
    float maskf, float r0, float r1, float r2,
    const float (&L)[27])
{
    const float px = rx * d0, py = ry * d0, pz = rz * d0;
    const float ax = (rx + i00) * dR - px;     // pl - p
    const float ay = (ry + i10) * dR - py;
    const float az = (rz + i20) * dR - pz;
    const float bx = (rx + i01) * dD - px;     // pu - p
    const float by = (ry + i11) * dD - py;
    const float bz = (rz + i21) * dD - pz;
    float nx = ay * bz - az * by;
    float ny = az * bx - ax * bz;
    float nz = ax * by - ay * bx;
    const float nn  = nx * nx + ny * ny + nz * nz;
    // 1/max(sqrt(nn),1e-12) == rsq(max(nn,1e-24)); v_rsq_f32 is ~1ulp.
    const float inr = __builtin_amdgcn_rsqf(fmaxf(nn, 1e-24f));
    nx *= inr; ny *= inr; nz *= inr;
    const float h4 = nx * ny, h5 = ny * nz, h7 = nz * nx;
    const float nx2 = nx * nx, ny2 = ny * ny, nz2 = nz * nz;
    const float h6 = 2.0f * nz2 - nx2 - ny2;
    const float h8 = nx2 - ny2;
    const float B0 = L[0] + ny*L[3] + nz*L[6] + nx*L[9]  + h4*L[12] + h5*L[15] + h6*L[18] + h7*L[21] + h8*L[24];
    const float B1 = L[1] + ny*L[4] + nz*L[7] + nx*L[10] + h4*L[13] + h5*L[16] + h6*L[19] + h7*L[22] + h8*L[25];
    const float B2 = L[2] + ny*L[5] + nz*L[8] + nx*L[11] + h4*L[14] + h5*L[17] + h6*L[20] + h7*L[23] + h8*L[26];
    return make_float4(fmaf(maskf, B0, -r0),
                       fmaf(maskf, B1, -r1),
                       fmaf(maskf, B2, -r2),
                       maskf);
}

__global__ __launch_bounds__(256) void shading_main(
    const float* __restrict__ depth,
    const float* __restrict__ rgb,
    const int*   __restrict__ mask,
    const float* __restrict__ lmat,   // [9][3]
    const float* __restrict__ K,      // [3][3]
    float* __restrict__ accum,        // partial {S,C} pairs
    int direct)                       // 1: accum[2*bid]=..., 0: atomic into bins
{
    __shared__ float4 qs[EXT_ROWS * QPITCH];
    __shared__ float sS[4], sC[4];

    const int tid = threadIdx.x;
    const int w0  = blockIdx.x * TW;
    const int h0  = blockIdx.y * TH;

    // ---- Kinv (general adjugate/det; uniform) ----
    const float m00 = K[0], m01 = K[1], m02 = K[2];
    const float m10 = K[3], m11 = K[4], m12 = K[5];
    const float m20 = K[6], m21 = K[7], m22 = K[8];
    const float det = m00*(m11*m22 - m12*m21)
                    - m01*(m10*m22 - m12*m20)
                    + m02*(m10*m21 - m11*m20);
    const float id  = 1.0f / det;
    const float i00 = (m11*m22 - m12*m21) * id;
    const float i01 = (m02*m21 - m01*m22) * id;
    const float i02 = (m01*m12 - m02*m11) * id;
    const float i10 = (m12*m20 - m10*m22) * id;
    const float i11 = (m00*m22 - m02*m20) * id;
    const float i12 = (m02*m10 - m00*m12) * id;
    const float i20 = (m10*m21 - m11*m20) * id;
    const float i21 = (m01*m20 - m00*m21) * id;
    const float i22 = (m00*m11 - m01*m10) * id;

    float L[27];
    #pragma unroll
    for (int i = 0; i < 27; ++i) L[i] = lmat[i];   // uniform -> s_load

    // ---- Phase 1: q over extended tile, 4-col groups, vector loads ----
    for (unsigned u = tid; u < NUNITS; u += 256) {
        const unsigned r = u / 18u;                 // ext row 0..17
        const unsigned j = u - r * 18u;             // col group 0..17
        const int gh  = h0 - 1 + (int)r;
        const int gw0 = w0 - 4 + (int)(j * 4u);
        float4* dst = &qs[r * QPITCH + j * 4u];

        const bool fast = (gh >= 0) & (gh < H_IMG) & (gw0 >= 0) & (gw0 + 4 < W_IMG);
        if (fast) {
            const int pix = gh * W_IMG + gw0;
            const float4 dc = *(const float4*)(depth + pix);
            const float dr4 = depth[pix + 4];
            float4 dn = make_float4(0.f, 0.f, 0.f, 0.f);
            if (gh + 1 < H_IMG) dn = *(const float4*)(depth + pix + W_IMG);
            const int4  mv = *(const int4*)(mask + pix);
            const float4 ra = *(const float4*)(rgb + pix * 3);
            const float4 rb = *(const float4*)(rgb + pix * 3 + 4);
            const float4 rc = *(const float4*)(rgb + pix * 3 + 8);

            float rx = fmaf(i00, (float)gw0, fmaf(i01, (float)gh, i02));
            float ry = fmaf(i10, (float)gw0, fmaf(i11, (float)gh, i12));
            float rz = fmaf(i20, (float)gw0, fmaf(i21, (float)gh, i22));

            const float dcur[5] = {dc.x, dc.y, dc.z, dc.w, dr4};
            const float ddn[4]  = {dn.x, dn.y, dn.z, dn.w};
            const float rr[12]  = {ra.x, ra.y, ra.z, ra.w,
                                   rb.x, rb.y, rb.z, rb.w,
                                   rc.x, rc.y, rc.z, rc.w};
            const int   mm[4]   = {mv.x, mv.y, mv.z, mv.w};
            #pragma unroll
            for (int k = 0; k < 4; ++k) {
                const float mf = (mm[k] > 0) ? 1.0f : 0.0f;
                dst[k] = shade_px(rx, ry, rz, i00, i10, i20, i01, i11, i21,
                                  dcur[k], dcur[k + 1], ddn[k],
                                  mf, rr[3*k], rr[3*k+1], rr[3*k+2], L);
                rx += i00; ry += i10; rz += i20;   // ray recurrence: +Kinv col0
            }
        } else {
            #pragma unroll
            for (int k = 0; k < 4; ++k) {
                const int gw = gw0 + k;
                float4 qv = make_float4(0.f, 0.f, 0.f, 0.f);
                if (gh >= 0 && gh < H_IMG && gw >= 0 && gw < W_IMG) {
                    const int pix = gh * W_IMG + gw;
                    const float d0 = depth[pix];
                    const float dR = (gw + 1 < W_IMG) ? depth[pix + 1] : 0.0f;
                    const float dD = (gh + 1 < H_IMG) ? depth[pix + W_IMG] : 0.0f;
                    const float mf = (mask[pix] > 0) ? 1.0f : 0.0f;
                    const float r0 = rgb[pix*3], r1 = rgb[pix*3+1], r2 = rgb[pix*3+2];
                    const float rx = fmaf(i00, (float)gw, fmaf(i01, (float)gh, i02));
                    const float ry = fmaf(i10, (float)gw, fmaf(i11, (float)gh, i12));
                    const float rz = fmaf(i20, (float)gw, fmaf(i21, (float)gh, i22));
                    qv = shade_px(rx, ry, rz, i00, i10, i20, i01, i11, i21,
                                  d0, dR, dD, mf, r0, r1, r2, L);
                }
                dst[k] = qv;
            }
        }
    }
    __syncthreads();

    // ---- Phase 2: 4 vertical centers/thread; diff = q - sum3x3(q)/9 ----
    const int tx = tid & 63;          // col within tile (lane stride = 16B: b128 floor)
    const int tq = tid >> 6;          // row quad 0..3 -> center rows h0+4*tq+k
    float rs0[6], rs1[6], rs2[6];
    float4 cv[4];
    #pragma unroll
    for (int r = 0; r < 6; ++r) {     // window ext rows 4tq .. 4tq+5, cols tx+3..tx+5
        const float4* rowp = &qs[(4 * tq + r) * QPITCH + tx + 3];
        const float4 a = rowp[0], b = rowp[1], c = rowp[2];
        rs0[r] = a.x + b.x + c.x;
        rs1[r] = a.y + b.y + c.y;
        rs2[r] = a.z + b.z + c.z;
        if (r >= 1 && r <= 4) cv[r - 1] = b;   // center col = +1, rows 4tq+1..4tq+4
    }
    float S = 0.f, C = 0.f;
    #pragma unroll
    for (int k = 0; k < 4; ++k) {
        const float s0 = rs0[k] + rs0[k+1] + rs0[k+2];
        const float s1 = rs1[k] + rs1[k+1] + rs1[k+2];
        const float s2 = rs2[k] + rs2[k+1] + rs2[k+2];
        const float d0 = cv[k].x - s0 * (1.0f/9.0f);
        const float d1 = cv[k].y - s1 * (1.0f/9.0f);
        const float d2 = cv[k].z - s2 * (1.0f/9.0f);
        const float m  = cv[k].w;
        S = fmaf(m, d0*d0 + d1*d1 + d2*d2, S);
        C += m;
    }

    // ---- Phase 3: block reduce -> store/atomic ----
    #pragma unroll
    for (int off = 32; off > 0; off >>= 1) {
        S += __shfl_down(S, off, 64);
        C += __shfl_down(C, off, 64);
    }
    const int wid = tid >> 6, lane = tid & 63;
    if (lane == 0) { sS[wid] = S; sC[wid] = C; }
    __syncthreads();
    if (tid == 0) {
        const float ts = sS[0] + sS[1] + sS[2] + sS[3];
        const float tc = sC[0] + sC[1] + sC[2] + sC[3];
        const int bid = blockIdx.y * gridDim.x + blockIdx.x;
        if (direct) {
            accum[2*bid + 0] = ts;              // no memset, no atomics
            accum[2*bid + 1] = tc;
        } else {
            const int bin = bid & (NBINS - 1);
            atomicAdd(&accum[2*bin + 0], ts);
            atomicAdd(&accum[2*bin + 1], tc);
        }
    }
}

__global__ __launch_bounds__(256) void finalize_kernel(
    const float* __restrict__ part, int n, float* __restrict__ out)
{
    const int tid = threadIdx.x;
    float s = 0.f, c = 0.f;
    for (int i = tid; i < n; i += 256) {
        s += part[2*i + 0];
        c += part[2*i + 1];
    }
    #pragma unroll
    for (int off = 32; off > 0; off >>= 1) {
        s += __shfl_down(s, off, 64);
        c += __shfl_down(c, off, 64);
    }
    __shared__ float sS[4], sC[4];
    const int wid = tid >> 6, lane = tid & 63;
    if (lane == 0) { sS[wid] = s; sC[wid] = c; }
    __syncthreads();
    if (tid == 0) {
        const float ts = sS[0] + sS[1] + sS[2] + sS[3];
        const float tc = sC[0] + sC[1] + sC[2] + sC[3];
        out[0] = ts / (3.0f * tc);
    }
}

extern "C" void kernel_launch(void* const* d_in, const int* in_sizes, int n_in,
                              void* d_out, int out_size, void* d_ws, size_t ws_size,
                              hipStream_t stream) {
    const float* depth = (const float*)d_in[0];   // [2160][3840] f32
    const float* rgb   = (const float*)d_in[1];   // [2160][3840][3] f32
    const int*   mask  = (const int*)  d_in[2];   // [2160][3840] i32
    const float* lmat  = (const float*)d_in[3];   // [9][3] f32
    const float* K     = (const float*)d_in[4];   // [3][3] f32
    float* accum = (float*)d_ws;
    float* out   = (float*)d_out;

    const dim3 grid(W_IMG / TW, H_IMG / TH);      // 60 x 135 = 8100 blocks
    const int nblocks = (W_IMG / TW) * (H_IMG / TH);

    if (ws_size >= (size_t)nblocks * 2 * sizeof(float)) {
        // Direct per-block partials: no memset, no atomics.
        shading_main<<<grid, 256, 0, stream>>>(depth, rgb, mask, lmat, K, accum, 1);
        finalize_kernel<<<1, 256, 0, stream>>>(accum, nblocks, out);
    } else {
        hipMemsetAsync(accum, 0, NBINS * 2 * sizeof(float), stream);
        shading_main<<<grid, 256, 0, stream>>>(depth, rgb, mask, lmat, K, accum, 0);
        finalize_kernel<<<1, 256, 0, stream>>>(accum, NBINS, out);
    }
}